// Round 4
// baseline (272.350 us; speedup 1.0000x reference)
//
#include <hip/hip_runtime.h>

// StructuralLoss: windowed ZNCC loss, sigma=4 -> w=2 (4x4 box windows).
// Register-streaming, no LDS staging. Each thread owns 4 output columns,
// streams RY=16 rows (1024 blocks = 4 blocks/CU = 16 waves/CU).
//
// R2 lesson: never force min-waves in __launch_bounds__ (VGPR cap 64 ->
// full scratch spill, 1.6 GB traffic, 460 us).
// R3 lesson: time/wave-step is constant vs occupancy (~800 cy/CU) ->
// serialized per-CU resource, suspected L1I thrash from ~40 KB unrolled
// body. This round: ROLLED outer loop (#pragma unroll 1) over a 4-phase
// body (~8 KB hot code), 3 peeled warm-up steps, emit via template bool.

#define HH 4096
#define WW 4096
constexpr int RY = 16;            // output rows per thread
constexpr float EPf = 1e-12f;     // clamp floor (ref 1e-20; typical variance ~0.1)

struct ThreadState {
    // raw row ring: [slot][10 cols] = raw cols j0-2 .. j0+7
    float A[4][10];
    float B[4][10];
    // H rings: [slot][4 output cols]
    float Hii[4][4], Hjj[4][4], Hij[4][4];
    float cmask[7];               // c-column validity (cols j0-1 .. j0+5)
    float acc;
};

__device__ __forceinline__ float4 zero4() { return make_float4(0.f, 0.f, 0.f, 0.f); }

// Load raw row t (both images) into ring slot SLOT (10 floats: cols j0-2..j0+7).
template <int SLOT>
__device__ __forceinline__ void load_row(ThreadState& st,
                                         const float* __restrict__ i1,
                                         const float* __restrict__ i2,
                                         int t, int j0, bool okL, bool okR) {
    float4 a0, a1, a2, b0, b1, b2;
    if (t >= 0 && t < HH) {                       // wave-uniform branch
        const float* p1 = i1 + (long)t * WW + j0;
        const float* p2 = i2 + (long)t * WW + j0;
        a0 = okL ? *(const float4*)(p1 - 4) : zero4();
        a1 = *(const float4*)(p1);
        a2 = okR ? *(const float4*)(p1 + 4) : zero4();
        b0 = okL ? *(const float4*)(p2 - 4) : zero4();
        b1 = *(const float4*)(p2);
        b2 = okR ? *(const float4*)(p2 + 4) : zero4();
    } else {
        a0 = a1 = a2 = b0 = b1 = b2 = zero4();
    }
    st.A[SLOT][0] = a0.z; st.A[SLOT][1] = a0.w;
    st.A[SLOT][2] = a1.x; st.A[SLOT][3] = a1.y; st.A[SLOT][4] = a1.z; st.A[SLOT][5] = a1.w;
    st.A[SLOT][6] = a2.x; st.A[SLOT][7] = a2.y; st.A[SLOT][8] = a2.z; st.A[SLOT][9] = a2.w;
    st.B[SLOT][0] = b0.z; st.B[SLOT][1] = b0.w;
    st.B[SLOT][2] = b1.x; st.B[SLOT][3] = b1.y; st.B[SLOT][4] = b1.z; st.B[SLOT][5] = b1.w;
    st.B[SLOT][6] = b2.x; st.B[SLOT][7] = b2.y; st.B[SLOT][8] = b2.z; st.B[SLOT][9] = b2.w;
}

// One streaming step. rr = rrb + K (iteration index); produces c-row
// r = y0-1+rr, loads raw row r+2 into ring slot K (== rr & 3), writes
// H ring slot K, and (if EMIT) accumulates output row r-2.
template <int K, bool EMIT>
__device__ __forceinline__ void step(ThreadState& st,
                                     const float* __restrict__ i1,
                                     const float* __restrict__ i2,
                                     int rrb, int y0, int j0, bool okL, bool okR) {
    const int rr = rrb + K;
    const int r  = y0 - 1 + rr;

    load_row<K>(st, i1, i2, r + 2, j0, okL, okR);

    // vertical 4-sums over the ring (raw rows r-1..r+2), all 10 cols
    float vs1[10], vs2[10];
#pragma unroll
    for (int m = 0; m < 10; ++m) {
        vs1[m] = st.A[0][m] + st.A[1][m] + st.A[2][m] + st.A[3][m];
        vs2[m] = st.B[0][m] + st.B[1][m] + st.B[2][m] + st.B[3][m];
    }

    constexpr int CS = (K + 2) & 3;  // slot holding raw row r (center)
    const float rmask = (r >= 0 && r < HH) ? 1.f : 0.f;

    // centered values at 7 c-columns (global col j0-1+k)
    float c1[7], c2[7];
#pragma unroll
    for (int k = 0; k < 7; ++k) {
        float mu1 = (vs1[k] + vs1[k + 1] + vs1[k + 2] + vs1[k + 3]) * 0.0625f;
        float mu2 = (vs2[k] + vs2[k + 1] + vs2[k + 2] + vs2[k + 3]) * 0.0625f;
        float msk = rmask * st.cmask[k];
        c1[k] = (st.A[CS][k + 1] - mu1) * msk;
        c2[k] = (st.B[CS][k + 1] - mu2) * msk;
    }

    // horizontal 4-sums of products for the 4 output columns -> H ring slot K
#pragma unroll
    for (int q = 0; q < 4; ++q) {
        float hii = 0.f, hjj = 0.f, hij = 0.f;
#pragma unroll
        for (int s = 0; s < 4; ++s) {
            float a = c1[q + s], b = c2[q + s];
            hii += a * a;
            hjj += b * b;
            hij += a * b;
        }
        st.Hii[K][q] = hii; st.Hjj[K][q] = hjj; st.Hij[K][q] = hij;
    }

    if (EMIT) {
#pragma unroll
        for (int q = 0; q < 4; ++q) {
            float sii = st.Hii[0][q] + st.Hii[1][q] + st.Hii[2][q] + st.Hii[3][q];
            float sjj = st.Hjj[0][q] + st.Hjj[1][q] + st.Hjj[2][q] + st.Hjj[3][q];
            float sij = st.Hij[0][q] + st.Hij[1][q] + st.Hij[2][q] + st.Hij[3][q];
            sii = fmaxf(sii, EPf);
            sjj = fmaxf(sjj, EPf);
            float L = sij * rsqrtf(sii * sjj);
            L = fmaxf(L, -1.f);
            st.acc += 1.f - L;
        }
    }
}

__global__ __launch_bounds__(256) void xcorr_loss_kernel(
    const float* __restrict__ img1, const float* __restrict__ img2,
    float* __restrict__ partial) {
    const int tcol = blockIdx.x * blockDim.x + threadIdx.x;  // thread col-group
    const int j0   = tcol * 4;
    const int y0   = blockIdx.y * RY;

    ThreadState st;
    st.acc = 0.f;
#pragma unroll
    for (int k = 0; k < 7; ++k) {
        int cc = j0 - 1 + k;
        st.cmask[k] = (cc >= 0 && cc < WW) ? 1.f : 0.f;
    }
    const bool okL = (j0 - 4) >= 0;
    const bool okR = (j0 + 7) < WW;

    // prime: raw rows y0-2, y0-1, y0 into ring slots 1,2,3
    load_row<1>(st, img1, img2, y0 - 2, j0, okL, okR);
    load_row<2>(st, img1, img2, y0 - 1, j0, okL, okR);
    load_row<3>(st, img1, img2, y0,     j0, okL, okR);

    // peeled warm-up: rr = 0,1,2 (fill H ring slots 0,1,2; no emit)
    step<0, false>(st, img1, img2, 0, y0, j0, okL, okR);
    step<1, false>(st, img1, img2, 0, y0, j0, okL, okR);
    step<2, false>(st, img1, img2, 0, y0, j0, okL, okR);

    // steady state: rr = 3..18, 16 emitting steps, ROLLED outer loop so the
    // hot body is only 4 steps of code (I$-resident).
#pragma unroll 1
    for (int o = 0; o < 4; ++o) {
        const int rrb = o * 4;
        step<3, true>(st, img1, img2, rrb,     y0, j0, okL, okR);  // rr = rrb+3
        step<0, true>(st, img1, img2, rrb + 4, y0, j0, okL, okR);  // rr = rrb+4
        step<1, true>(st, img1, img2, rrb + 4, y0, j0, okL, okR);  // rr = rrb+5
        step<2, true>(st, img1, img2, rrb + 4, y0, j0, okL, okR);  // rr = rrb+6
    }

    // wave (64) shuffle reduce, then LDS across the block's 4 waves
    float wsum = st.acc;
#pragma unroll
    for (int off = 32; off > 0; off >>= 1)
        wsum += __shfl_down(wsum, off, 64);

    __shared__ float red[4];
    const int lane = threadIdx.x & 63;
    const int wid  = threadIdx.x >> 6;
    if (lane == 0) red[wid] = wsum;
    __syncthreads();
    if (threadIdx.x == 0) {
        float bsum = red[0] + red[1] + red[2] + red[3];
        partial[blockIdx.y * gridDim.x + blockIdx.x] = bsum;
    }
}

__global__ __launch_bounds__(256) void finalize_kernel(
    const float* __restrict__ partial, int nb, float* __restrict__ out) {
    double s = 0.0;
    for (int i = threadIdx.x; i < nb; i += 256)
        s += (double)partial[i];
#pragma unroll
    for (int off = 32; off > 0; off >>= 1)
        s += __shfl_down(s, off, 64);
    __shared__ double red[4];
    const int lane = threadIdx.x & 63;
    const int wid  = threadIdx.x >> 6;
    if (lane == 0) red[wid] = s;
    __syncthreads();
    if (threadIdx.x == 0) {
        double tot = red[0] + red[1] + red[2] + red[3];
        double mean = tot / ((double)HH * (double)WW);
        out[0] = (float)mean;
        out[1] = (float)mean;
    }
}

extern "C" void kernel_launch(void* const* d_in, const int* in_sizes, int n_in,
                              void* d_out, int out_size, void* d_ws, size_t ws_size,
                              hipStream_t stream) {
    const float* img1 = (const float*)d_in[0];  // outputs
    const float* img2 = (const float*)d_in[1];  // labels
    float* partial = (float*)d_ws;              // 1024 floats

    dim3 grid(WW / (256 * 4), HH / RY);         // (4, 256) = 1024 blocks
    xcorr_loss_kernel<<<grid, dim3(256), 0, stream>>>(img1, img2, partial);
    finalize_kernel<<<1, 256, 0, stream>>>(partial, grid.x * grid.y, (float*)d_out);
}

// Round 5
// 230.215 us; speedup vs baseline: 1.1830x; 1.1830x over previous
//
#include <hip/hip_runtime.h>

// StructuralLoss: windowed ZNCC loss, sigma=4 -> w=2 (4x4 box windows).
// Register-streaming + distance-1 software prefetch. Each thread owns 4
// output columns, streams RY=16 rows. Loads for step k+1 are issued during
// step k's compute (~1300 cy cover > 900 cy HBM latency).
//
// R2 lesson: never force min-waves via __launch_bounds__ (VGPR cap 64 ->
//   full scratch spill, 1.6 GB traffic, 460 us). Natural alloc only.
// R4 lesson: rolled loop regressed (blocks cross-step load hoisting,
//   adds loop-carried copies). Full unroll is the right shape.
// R3 lesson: per-wave-step cost ~3000 cy regardless of occupancy ->
//   exposed per-step load latency is the bottleneck; this round makes the
//   prefetch structural instead of hoping waves cover it.

#define HH 4096
#define WW 4096
constexpr int RY = 16;            // output rows per thread
constexpr float EPf = 1e-12f;     // clamp floor (ref 1e-20; typical variance ~0.1)

struct ThreadState {
    // raw row ring: [slot][10 cols] = raw cols j0-2 .. j0+7
    float A[4][10];
    float B[4][10];
    // prefetch staging (raw float4s of the next row, both images)
    float4 Pa0, Pa1, Pa2, Pb0, Pb1, Pb2;
    // H rings: [slot][4 output cols]
    float Hii[4][4], Hjj[4][4], Hij[4][4];
    float mskL, mskR;             // x-border masks (k=0 / k=5,6)
    float acc;
};

__device__ __forceinline__ float4 zero4() { return make_float4(0.f, 0.f, 0.f, 0.f); }

// Issue loads of raw row t (both images) into the prefetch float4s.
__device__ __forceinline__ void load_P(ThreadState& st,
                                       const float* __restrict__ i1,
                                       const float* __restrict__ i2,
                                       int t, int j0, bool okL, bool okR) {
    if (t >= 0 && t < HH) {                       // wave-uniform branch
        const float* p1 = i1 + (long)t * WW + j0;
        const float* p2 = i2 + (long)t * WW + j0;
        st.Pa0 = okL ? *(const float4*)(p1 - 4) : zero4();
        st.Pa1 = *(const float4*)(p1);
        st.Pa2 = okR ? *(const float4*)(p1 + 4) : zero4();
        st.Pb0 = okL ? *(const float4*)(p2 - 4) : zero4();
        st.Pb1 = *(const float4*)(p2);
        st.Pb2 = okR ? *(const float4*)(p2 + 4) : zero4();
    } else {
        st.Pa0 = st.Pa1 = st.Pa2 = zero4();
        st.Pb0 = st.Pb1 = st.Pb2 = zero4();
    }
}

// Commit the prefetched row into ring slot SLOT (10 cols: j0-2 .. j0+7).
template <int SLOT>
__device__ __forceinline__ void commit(ThreadState& st) {
    st.A[SLOT][0] = st.Pa0.z; st.A[SLOT][1] = st.Pa0.w;
    st.A[SLOT][2] = st.Pa1.x; st.A[SLOT][3] = st.Pa1.y;
    st.A[SLOT][4] = st.Pa1.z; st.A[SLOT][5] = st.Pa1.w;
    st.A[SLOT][6] = st.Pa2.x; st.A[SLOT][7] = st.Pa2.y;
    st.A[SLOT][8] = st.Pa2.z; st.A[SLOT][9] = st.Pa2.w;
    st.B[SLOT][0] = st.Pb0.z; st.B[SLOT][1] = st.Pb0.w;
    st.B[SLOT][2] = st.Pb1.x; st.B[SLOT][3] = st.Pb1.y;
    st.B[SLOT][4] = st.Pb1.z; st.B[SLOT][5] = st.Pb1.w;
    st.B[SLOT][6] = st.Pb2.x; st.B[SLOT][7] = st.Pb2.y;
    st.B[SLOT][8] = st.Pb2.z; st.B[SLOT][9] = st.Pb2.w;
}

// One streaming step at iteration rr (compile-time ring phase K = rr&3).
// Commits prefetched raw row r+2 into slot K, issues prefetch of r+3
// (if LIVE), computes c-row r and H slot K, emits output row r-2 if EMIT.
template <int K, bool EMIT, bool LIVE>
__device__ __forceinline__ void step(ThreadState& st,
                                     const float* __restrict__ i1,
                                     const float* __restrict__ i2,
                                     int rr, int y0, int j0, bool okL, bool okR) {
    const int r = y0 - 1 + rr;

    // commit prefetched raw row r+2 (issued one full step ago)
    commit<K>(st);
    // issue prefetch of raw row r+3 for the NEXT step
    if (LIVE) load_P(st, i1, i2, r + 3, j0, okL, okR);

    // vertical 4-sums over the ring (raw rows r-1..r+2), all 10 cols
    float vs1[10], vs2[10];
#pragma unroll
    for (int m = 0; m < 10; ++m) {
        vs1[m] = (st.A[0][m] + st.A[1][m]) + (st.A[2][m] + st.A[3][m]);
        vs2[m] = (st.B[0][m] + st.B[1][m]) + (st.B[2][m] + st.B[3][m]);
    }
    // hierarchical horizontal 4-window sums of the vertical sums
    float p1[9], p2[9];
#pragma unroll
    for (int m = 0; m < 9; ++m) { p1[m] = vs1[m] + vs1[m + 1]; p2[m] = vs2[m] + vs2[m + 1]; }

    constexpr int CS = (K + 2) & 3;  // slot holding raw row r (center)
    const float rmask = (r >= 0 && r < HH) ? 1.f : 0.f;
    const float m0 = rmask * st.mskL;   // k == 0
    const float mR = rmask * st.mskR;   // k == 5, 6

    // centered values at 7 c-columns (global col j0-1+k)
    float c1[7], c2[7];
#pragma unroll
    for (int k = 0; k < 7; ++k) {
        float s1 = p1[k] + p1[k + 2];
        float s2 = p2[k] + p2[k + 2];
        float msk = (k == 0) ? m0 : (k >= 5 ? mR : rmask);
        c1[k] = fmaf(-0.0625f, s1, st.A[CS][k + 1]) * msk;
        c2[k] = fmaf(-0.0625f, s2, st.B[CS][k + 1]) * msk;
    }

    // horizontal 4-sums of products for the 4 output columns -> H ring slot K
#pragma unroll
    for (int q = 0; q < 4; ++q) {
        float hii = c1[q] * c1[q];
        float hjj = c2[q] * c2[q];
        float hij = c1[q] * c2[q];
#pragma unroll
        for (int s = 1; s < 4; ++s) {
            float a = c1[q + s], b = c2[q + s];
            hii = fmaf(a, a, hii);
            hjj = fmaf(b, b, hjj);
            hij = fmaf(a, b, hij);
        }
        st.Hii[K][q] = hii; st.Hjj[K][q] = hjj; st.Hij[K][q] = hij;
    }

    if (EMIT) {
#pragma unroll
        for (int q = 0; q < 4; ++q) {
            float sii = (st.Hii[0][q] + st.Hii[1][q]) + (st.Hii[2][q] + st.Hii[3][q]);
            float sjj = (st.Hjj[0][q] + st.Hjj[1][q]) + (st.Hjj[2][q] + st.Hjj[3][q]);
            float sij = (st.Hij[0][q] + st.Hij[1][q]) + (st.Hij[2][q] + st.Hij[3][q]);
            sii = fmaxf(sii, EPf);
            sjj = fmaxf(sjj, EPf);
            float L = sij * rsqrtf(sii * sjj);
            L = fmaxf(L, -1.f);
            st.acc += 1.f - L;
        }
    }
}

__global__ __launch_bounds__(256) void xcorr_loss_kernel(
    const float* __restrict__ img1, const float* __restrict__ img2,
    float* __restrict__ partial) {
    const int tcol = blockIdx.x * blockDim.x + threadIdx.x;  // thread col-group
    const int j0   = tcol * 4;
    const int y0   = blockIdx.y * RY;

    ThreadState st;
    st.acc  = 0.f;
    // x-border c-masks: k=0 -> col j0-1, k=5 -> j0+4, k=6 -> j0+5.
    // For j0 in {0,4,...,4092}: k=0 invalid iff j0==0; k=5,6 invalid iff j0==4092.
    st.mskL = (j0 > 0) ? 1.f : 0.f;
    st.mskR = (j0 < WW - 4) ? 1.f : 0.f;
    const bool okL = (j0 - 4) >= 0;
    const bool okR = (j0 + 7) < WW;

    // prime: raw rows y0-2, y0-1, y0 into ring slots 1,2,3 (via P + commit)
    load_P(st, img1, img2, y0 - 2, j0, okL, okR); commit<1>(st);
    load_P(st, img1, img2, y0 - 1, j0, okL, okR); commit<2>(st);
    load_P(st, img1, img2, y0,     j0, okL, okR); commit<3>(st);
    // prefetch raw row y0+1 (committed in step rr=0)
    load_P(st, img1, img2, y0 + 1, j0, okL, okR);

    // rr = 0..18, fully unrolled; emit for rr >= 3; last step issues no load
    step<0, false, true>(st, img1, img2, 0,  y0, j0, okL, okR);
    step<1, false, true>(st, img1, img2, 1,  y0, j0, okL, okR);
    step<2, false, true>(st, img1, img2, 2,  y0, j0, okL, okR);
    step<3, true,  true>(st, img1, img2, 3,  y0, j0, okL, okR);
    step<0, true,  true>(st, img1, img2, 4,  y0, j0, okL, okR);
    step<1, true,  true>(st, img1, img2, 5,  y0, j0, okL, okR);
    step<2, true,  true>(st, img1, img2, 6,  y0, j0, okL, okR);
    step<3, true,  true>(st, img1, img2, 7,  y0, j0, okL, okR);
    step<0, true,  true>(st, img1, img2, 8,  y0, j0, okL, okR);
    step<1, true,  true>(st, img1, img2, 9,  y0, j0, okL, okR);
    step<2, true,  true>(st, img1, img2, 10, y0, j0, okL, okR);
    step<3, true,  true>(st, img1, img2, 11, y0, j0, okL, okR);
    step<0, true,  true>(st, img1, img2, 12, y0, j0, okL, okR);
    step<1, true,  true>(st, img1, img2, 13, y0, j0, okL, okR);
    step<2, true,  true>(st, img1, img2, 14, y0, j0, okL, okR);
    step<3, true,  true>(st, img1, img2, 15, y0, j0, okL, okR);
    step<0, true,  true>(st, img1, img2, 16, y0, j0, okL, okR);
    step<1, true,  true>(st, img1, img2, 17, y0, j0, okL, okR);
    step<2, true,  false>(st, img1, img2, 18, y0, j0, okL, okR);

    // wave (64) shuffle reduce, then LDS across the block's 4 waves
    float wsum = st.acc;
#pragma unroll
    for (int off = 32; off > 0; off >>= 1)
        wsum += __shfl_down(wsum, off, 64);

    __shared__ float red[4];
    const int lane = threadIdx.x & 63;
    const int wid  = threadIdx.x >> 6;
    if (lane == 0) red[wid] = wsum;
    __syncthreads();
    if (threadIdx.x == 0) {
        float bsum = red[0] + red[1] + red[2] + red[3];
        partial[blockIdx.y * gridDim.x + blockIdx.x] = bsum;
    }
}

__global__ __launch_bounds__(256) void finalize_kernel(
    const float* __restrict__ partial, int nb, float* __restrict__ out) {
    double s = 0.0;
    for (int i = threadIdx.x; i < nb; i += 256)
        s += (double)partial[i];
#pragma unroll
    for (int off = 32; off > 0; off >>= 1)
        s += __shfl_down(s, off, 64);
    __shared__ double red[4];
    const int lane = threadIdx.x & 63;
    const int wid  = threadIdx.x >> 6;
    if (lane == 0) red[wid] = s;
    __syncthreads();
    if (threadIdx.x == 0) {
        double tot = red[0] + red[1] + red[2] + red[3];
        double mean = tot / ((double)HH * (double)WW);
        out[0] = (float)mean;
        out[1] = (float)mean;
    }
}

extern "C" void kernel_launch(void* const* d_in, const int* in_sizes, int n_in,
                              void* d_out, int out_size, void* d_ws, size_t ws_size,
                              hipStream_t stream) {
    const float* img1 = (const float*)d_in[0];  // outputs
    const float* img2 = (const float*)d_in[1];  // labels
    float* partial = (float*)d_ws;              // 1024 floats

    dim3 grid(WW / (256 * 4), HH / RY);         // (4, 256) = 1024 blocks
    xcorr_loss_kernel<<<grid, dim3(256), 0, stream>>>(img1, img2, partial);
    finalize_kernel<<<1, 256, 0, stream>>>(partial, grid.x * grid.y, (float*)d_out);
}

// Round 6
// 192.655 us; speedup vs baseline: 1.4137x; 1.1950x over previous
//
#include <hip/hip_runtime.h>

// StructuralLoss: windowed ZNCC loss, sigma=4 -> w=2 (4x4 box windows).
//
// R1-R5 finding: per-CU throughput pinned at ~8 issued-VMEM-bytes/cy — the
// measured VMEM streaming ceiling (m13: 10.2 B/cy/CU). The p-4/p/p+4 triple
// load fetched every line ~3x. THIS ROUND: one float4 load per image per
// step (lane's own 4 cols only); x-halo via __shfl of running vertical
// sums + center-row raw. Wave strips overlap one lane per side (lanes 1..62
// productive). Running vs (+= new - old) shrinks the raw ring to 4x4.
// R2 lesson: never force min-waves via __launch_bounds__ (spill disaster).
// R4 lesson: rolled loop OK only if ring phases need no rotation movs
//   (phase period == ring size) and loads are explicitly prefetched.

#define HH 4096
#define WW 4096
constexpr int RY     = 32;        // output rows per wave-strip
constexpr int GROUPS = 1024;      // 4-col output groups across the image
constexpr int PROD   = 62;        // productive lanes per wave
constexpr int WAVES_X = (GROUPS + PROD - 1) / PROD;   // 17
constexpr float EPf  = 1e-12f;    // clamp floor (ref 1e-20; variance ~0.1)

struct TS {
    float A[4][4], B[4][4];                    // raw ring, own 4 cols
    float vsA[4], vsB[4];                      // running vertical 4-sums
    float Hii[4][4], Hjj[4][4], Hij[4][4];     // H ring [slot][own col]
    float4 Pa, Pb;                             // prefetched next raw row
    float acc;
};

__device__ __forceinline__ void load_P(TS& st,
                                       const float* __restrict__ i1,
                                       const float* __restrict__ i2,
                                       int t, int j0c) {
    if (t >= 0 && t < HH) {                    // wave-uniform branch
        const float* p1 = i1 + (size_t)t * WW + j0c;
        const float* p2 = i2 + (size_t)t * WW + j0c;
        st.Pa = *(const float4*)p1;
        st.Pb = *(const float4*)p2;
    } else {
        st.Pa = make_float4(0.f, 0.f, 0.f, 0.f);
        st.Pb = make_float4(0.f, 0.f, 0.f, 0.f);
    }
}

template <int S>
__device__ __forceinline__ void prime_commit(TS& st) {
    st.A[S][0] = st.Pa.x; st.A[S][1] = st.Pa.y; st.A[S][2] = st.Pa.z; st.A[S][3] = st.Pa.w;
    st.B[S][0] = st.Pb.x; st.B[S][1] = st.Pb.y; st.B[S][2] = st.Pb.z; st.B[S][3] = st.Pb.w;
}

// One streaming step at iteration rr (ring phase K = rr&3). Commits
// prefetched raw row r+2 (r = y0-1+rr) into slot K updating running vs,
// prefetches row r+3, computes c-row r -> H ring slot K, emits output
// row r-2 if EMIT. lhz doubles as mskL, rhz as mskR (same conditions).
template <int K, bool EMIT>
__device__ __forceinline__ void step(TS& st,
                                     const float* __restrict__ i1,
                                     const float* __restrict__ i2,
                                     int rr, int y0, int j0c,
                                     float lhz, float rhz) {
    const int r = y0 - 1 + rr;

    // commit prefetched row r+2, update running vertical sums
    float pa[4] = {st.Pa.x, st.Pa.y, st.Pa.z, st.Pa.w};
    float pb[4] = {st.Pb.x, st.Pb.y, st.Pb.z, st.Pb.w};
#pragma unroll
    for (int m = 0; m < 4; ++m) {
        st.vsA[m] += pa[m] - st.A[K][m];  st.A[K][m] = pa[m];
        st.vsB[m] += pb[m] - st.B[K][m];  st.B[K][m] = pb[m];
    }
    // prefetch row r+3 for the next step
    load_P(st, i1, i2, r + 3, j0c);

    // vertical sums at 10 columns j0-3..j0+6 via lane shuffles
    // (halo zeroed at image borders: padded region is zeros)
    float va[10], vb[10];
    va[0] = __shfl_up(st.vsA[1], 1) * lhz;
    va[1] = __shfl_up(st.vsA[2], 1) * lhz;
    va[2] = __shfl_up(st.vsA[3], 1) * lhz;
    vb[0] = __shfl_up(st.vsB[1], 1) * lhz;
    vb[1] = __shfl_up(st.vsB[2], 1) * lhz;
    vb[2] = __shfl_up(st.vsB[3], 1) * lhz;
#pragma unroll
    for (int m = 0; m < 4; ++m) { va[3 + m] = st.vsA[m]; vb[3 + m] = st.vsB[m]; }
    va[7] = __shfl_down(st.vsA[0], 1) * rhz;
    va[8] = __shfl_down(st.vsA[1], 1) * rhz;
    va[9] = __shfl_down(st.vsA[2], 1) * rhz;
    vb[7] = __shfl_down(st.vsB[0], 1) * rhz;
    vb[8] = __shfl_down(st.vsB[1], 1) * rhz;
    vb[9] = __shfl_down(st.vsB[2], 1) * rhz;

    // center raw row r at c-cols j0-1..j0+5 (border cols masked later)
    constexpr int CS = (K + 2) & 3;
    float cr1[7], cr2[7];
    cr1[0] = __shfl_up(st.A[CS][3], 1);
    cr2[0] = __shfl_up(st.B[CS][3], 1);
#pragma unroll
    for (int m = 0; m < 4; ++m) { cr1[1 + m] = st.A[CS][m]; cr2[1 + m] = st.B[CS][m]; }
    cr1[5] = __shfl_down(st.A[CS][0], 1);
    cr1[6] = __shfl_down(st.A[CS][1], 1);
    cr2[5] = __shfl_down(st.B[CS][0], 1);
    cr2[6] = __shfl_down(st.B[CS][1], 1);

    const float rmask = (r >= 0 && r < HH) ? 1.f : 0.f;

    // mu window sums (hierarchical pairs) and centered values
    float pA[9], pB[9];
#pragma unroll
    for (int m = 0; m < 9; ++m) { pA[m] = va[m] + va[m + 1]; pB[m] = vb[m] + vb[m + 1]; }
    float c1[7], c2[7];
#pragma unroll
    for (int k = 0; k < 7; ++k) {
        float sA = pA[k] + pA[k + 2];
        float sB = pB[k] + pB[k + 2];
        float mk = (k == 0) ? rmask * lhz : (k >= 5 ? rmask * rhz : rmask);
        c1[k] = fmaf(-0.0625f, sA, cr1[k]) * mk;
        c2[k] = fmaf(-0.0625f, sB, cr2[k]) * mk;
    }

    // horizontal 4-window product sums -> H ring slot K
    float prii[7], prjj[7], prij[7];
#pragma unroll
    for (int k = 0; k < 7; ++k) {
        prii[k] = c1[k] * c1[k];
        prjj[k] = c2[k] * c2[k];
        prij[k] = c1[k] * c2[k];
    }
    float qii[6], qjj[6], qij[6];
#pragma unroll
    for (int m = 0; m < 6; ++m) {
        qii[m] = prii[m] + prii[m + 1];
        qjj[m] = prjj[m] + prjj[m + 1];
        qij[m] = prij[m] + prij[m + 1];
    }
#pragma unroll
    for (int q = 0; q < 4; ++q) {
        st.Hii[K][q] = qii[q] + qii[q + 2];
        st.Hjj[K][q] = qjj[q] + qjj[q + 2];
        st.Hij[K][q] = qij[q] + qij[q + 2];
    }

    if (EMIT) {
#pragma unroll
        for (int q = 0; q < 4; ++q) {
            float sii = (st.Hii[0][q] + st.Hii[1][q]) + (st.Hii[2][q] + st.Hii[3][q]);
            float sjj = (st.Hjj[0][q] + st.Hjj[1][q]) + (st.Hjj[2][q] + st.Hjj[3][q]);
            float sij = (st.Hij[0][q] + st.Hij[1][q]) + (st.Hij[2][q] + st.Hij[3][q]);
            sii = fmaxf(sii, EPf);
            sjj = fmaxf(sjj, EPf);
            float L = sij * rsqrtf(sii * sjj);
            L = fmaxf(L, -1.f);
            st.acc += 1.f - L;
        }
    }
}

__global__ __launch_bounds__(64) void xcorr_loss_kernel(
    const float* __restrict__ img1, const float* __restrict__ img2,
    float* __restrict__ partial) {
    const int lane = threadIdx.x & 63;
    const int g    = blockIdx.x * PROD + lane - 1;        // true col-group
    const int gc   = min(max(g, 0), GROUPS - 1);          // clamped for loads
    const int j0c  = gc * 4;
    const int y0   = blockIdx.y * RY;

    const float lhz = (gc == 0) ? 0.f : 1.f;              // left border (halo+mask)
    const float rhz = (gc == GROUPS - 1) ? 0.f : 1.f;     // right border
    const float em  = (lane >= 1 && lane <= 62 && g < GROUPS) ? 1.f : 0.f;

    TS st;
    st.acc = 0.f;
#pragma unroll
    for (int s = 0; s < 4; ++s)
#pragma unroll
        for (int q = 0; q < 4; ++q) {
            st.Hii[s][q] = 0.f; st.Hjj[s][q] = 0.f; st.Hij[s][q] = 0.f;
        }

    // prime: raw rows y0-3..y0 into slots 0..3; vs = their sum
    load_P(st, img1, img2, y0 - 3, j0c); prime_commit<0>(st);
    load_P(st, img1, img2, y0 - 2, j0c); prime_commit<1>(st);
    load_P(st, img1, img2, y0 - 1, j0c); prime_commit<2>(st);
    load_P(st, img1, img2, y0,     j0c); prime_commit<3>(st);
#pragma unroll
    for (int m = 0; m < 4; ++m) {
        st.vsA[m] = (st.A[0][m] + st.A[1][m]) + (st.A[2][m] + st.A[3][m]);
        st.vsB[m] = (st.B[0][m] + st.B[1][m]) + (st.B[2][m] + st.B[3][m]);
    }
    // initial prefetch: row y0+1 (committed at rr=0)
    load_P(st, img1, img2, y0 + 1, j0c);

    // warm-up rr=0..2 (fill H slots 0..2, no emit)
    step<0, false>(st, img1, img2, 0, y0, j0c, lhz, rhz);
    step<1, false>(st, img1, img2, 1, y0, j0c, lhz, rhz);
    step<2, false>(st, img1, img2, 2, y0, j0c, lhz, rhz);

    // steady state rr=3..34: 32 emitting steps, rolled over 4-phase groups
    // (phase period == ring size -> no rotation movs across the backedge)
#pragma unroll 1
    for (int o = 0; o < 8; ++o) {
        const int base = 4 * o + 3;
        step<3, true>(st, img1, img2, base,     y0, j0c, lhz, rhz);
        step<0, true>(st, img1, img2, base + 1, y0, j0c, lhz, rhz);
        step<1, true>(st, img1, img2, base + 2, y0, j0c, lhz, rhz);
        step<2, true>(st, img1, img2, base + 3, y0, j0c, lhz, rhz);
    }

    // wave reduction (single-wave block), one partial per block
    float wsum = em * st.acc;
#pragma unroll
    for (int off = 32; off > 0; off >>= 1)
        wsum += __shfl_down(wsum, off, 64);
    if (lane == 0)
        partial[blockIdx.y * gridDim.x + blockIdx.x] = wsum;
}

__global__ __launch_bounds__(256) void finalize_kernel(
    const float* __restrict__ partial, int nb, float* __restrict__ out) {
    double s = 0.0;
    for (int i = threadIdx.x; i < nb; i += 256)
        s += (double)partial[i];
#pragma unroll
    for (int off = 32; off > 0; off >>= 1)
        s += __shfl_down(s, off, 64);
    __shared__ double red[4];
    const int lane = threadIdx.x & 63;
    const int wid  = threadIdx.x >> 6;
    if (lane == 0) red[wid] = s;
    __syncthreads();
    if (threadIdx.x == 0) {
        double tot = red[0] + red[1] + red[2] + red[3];
        double mean = tot / ((double)HH * (double)WW);
        out[0] = (float)mean;
        out[1] = (float)mean;
    }
}

extern "C" void kernel_launch(void* const* d_in, const int* in_sizes, int n_in,
                              void* d_out, int out_size, void* d_ws, size_t ws_size,
                              hipStream_t stream) {
    const float* img1 = (const float*)d_in[0];  // outputs
    const float* img2 = (const float*)d_in[1];  // labels
    float* partial = (float*)d_ws;              // WAVES_X * (HH/RY) floats

    dim3 grid(WAVES_X, HH / RY);                // (17, 128) = 2176 blocks
    xcorr_loss_kernel<<<grid, dim3(64), 0, stream>>>(img1, img2, partial);
    finalize_kernel<<<1, 256, 0, stream>>>(partial, WAVES_X * (HH / RY), (float*)d_out);
}